// Round 3
// baseline (251.213 us; speedup 1.0000x reference)
//
#include <hip/hip_runtime.h>
#include <hip/hip_bf16.h>
#include <stdint.h>

// Problem constants (match reference)
#define NN 50000      // nodes
#define NE 800000     // edges
#define NL 100000     // label edges
#define SLOTS 64      // padded-CSR slots/node. deg~Poisson(16); P(deg>64)~1e-13.

// Bucketed CSR build (R7: direct scatter was line-bound)
#define NB 196        // dst-range buckets: bucket = dst >> 8 (256 nodes each)
#define BSH 8
#define BCAP 5376     // edges/bucket capacity; mean 4082 -> +20 sigma

typedef __attribute__((ext_vector_type(8))) short bf16x8;   // MFMA A/B frag
typedef __attribute__((ext_vector_type(4))) float f32x4;    // MFMA C/D frag
typedef __attribute__((ext_vector_type(4))) unsigned int u32x4;
typedef __attribute__((ext_vector_type(2))) unsigned int u32x2;
typedef __attribute__((ext_vector_type(8))) unsigned short u16x8;

__device__ __forceinline__ float asf(unsigned int u) {
    union { unsigned int i; float f; } c; c.i = u; return c.f;
}
__device__ __forceinline__ float bflo(unsigned int x) { return asf(x << 16); }
__device__ __forceinline__ float bfhi(unsigned int x) { return asf(x & 0xffff0000u); }
__device__ __forceinline__ unsigned short f2bf(float f) {
    union { float f; unsigned int i; } c; c.f = f;
    unsigned int u = c.i + (0x7fffu + ((c.i >> 16) & 1u));
    return (unsigned short)(u >> 16);
}

// ---- P0: W transpose+convert to bf16 Wt[n][k]; zero bucket cursors ----
__global__ void k_wprep(const float* __restrict__ W1, const float* __restrict__ W2,
                        const float* __restrict__ W3, unsigned short* __restrict__ Wt,
                        int* __restrict__ cursor) {
    int idx = blockIdx.x * 256 + threadIdx.x;   // grid exactly 160
    if (idx < NB) cursor[idx] = 0;
    const float* W; unsigned short* O; int base, Mloc;
    if (idx < 16384)      { W = W1; O = Wt;         base = idx;         Mloc = 128; }
    else if (idx < 32768) { W = W2; O = Wt + 16384; base = idx - 16384; Mloc = 128; }
    else                  { W = W3; O = Wt + 32768; base = idx - 32768; Mloc = 64;  }
    int n = base >> 7, k = base & 127;
    O[base] = f2bf(W[k * Mloc + n]);
}

// ---- P1: bin edges by dst range (LDS histogram -> packed NT writes) ----
__global__ __launch_bounds__(256) void k_bin(
        const int* __restrict__ src, const int* __restrict__ dst,
        int* __restrict__ cursor, unsigned int* __restrict__ binbuf) {
    __shared__ int hcnt[NB];
    __shared__ int hbase[NB];
    __shared__ unsigned int epk[2048];
    int tid = threadIdx.x;
    if (tid < NB) hcnt[tid] = 0;
    __syncthreads();
    int e0 = blockIdx.x * 2048;                 // grid exactly 391
    int e1 = min(e0 + 2048, NE);
    for (int e = e0 + tid; e < e1; e += 256) {
        int d = dst[e], s = src[e];
        atomicAdd(&hcnt[d >> BSH], 1);
        epk[e - e0] = (unsigned int)s | ((unsigned int)d << 16);
    }
    __syncthreads();
    if (tid < NB) { hbase[tid] = atomicAdd(&cursor[tid], hcnt[tid]); hcnt[tid] = 0; }
    __syncthreads();
    for (int e = e0 + tid; e < e1; e += 256) {
        unsigned int pk = epk[e - e0];
        int b = (int)(pk >> 16) >> BSH;
        int p = hbase[b] + atomicAdd(&hcnt[b], 1);
        if (p < BCAP)
            __builtin_nontemporal_store(pk, &binbuf[(size_t)b * BCAP + p]);
    }
}

// ---- P2: per-bucket CSR build in LDS + coalesced flush ----
// R15: slots < 32 stored PERMUTED: logical slot p at physical 8*(p&3)+(p>>2).
// So lane-group g's contiguous physical [8g,8g+8) holds logical slots
// {g, 4+g, ..., 28+g}: element k2 <-> logical 4*k2+g. Slots >=32 identity.
// Pad slots stay zeroed (gathers value-mask, pad reads row 0, L1-hot).
__global__ __launch_bounds__(256) void k_csr(
        const unsigned int* __restrict__ binbuf, const int* __restrict__ cursor,
        int* __restrict__ deg, unsigned short* __restrict__ colp) {
    __shared__ unsigned short lcol[256 * SLOTS];   // 32 KB
    __shared__ int ldeg[256];
    int tid = threadIdx.x;
    int blk = blockIdx.x;                          // grid exactly NB
    int base = blk << BSH;
    int nNodes = min(256, NN - base);
    ldeg[tid] = 0;
    u32x4* lz = (u32x4*)lcol;
#pragma unroll
    for (int i = 0; i < 8; ++i) lz[i * 256 + tid] = (u32x4){0, 0, 0, 0};
    __syncthreads();
    int cnt = min(cursor[blk], BCAP);
    for (int e = tid; e < cnt; e += 256) {
        unsigned int pk = __builtin_nontemporal_load(&binbuf[(size_t)blk * BCAP + e]);
        int d = (int)(pk >> 16) - base;
        int p = atomicAdd(&ldeg[d], 1);
        if (p < SLOTS) {
            int pp = (p < 32) ? ((p & 3) * 8 + (p >> 2)) : p;
            lcol[d * SLOTS + pp] = (unsigned short)(pk & 0xffffu);
        }
    }
    __syncthreads();
    if (tid < nNodes) deg[base + tid] = ldeg[tid];
    u32x4* gout = (u32x4*)(colp + (size_t)base * SLOTS);
    const u32x4* lin = (const u32x4*)lcol;
    for (int i = tid; i < nNodes * 8; i += 256) gout[i] = lin[i];
}

// ---- layer-1 GEMM: x (fp32) -> bufH. Zero LDS/barriers (R7 form) ----
__global__ __launch_bounds__(256) void k_gemm1(
        const float* __restrict__ A, const unsigned short* __restrict__ Wt,
        const int* __restrict__ deg, unsigned short* __restrict__ Outb, int N) {
    constexpr int K = 128;
    constexpr int NT = 8;
    int tid = threadIdx.x;
    int lane = tid & 63, wave = tid >> 6;
    int m = lane & 15, quad = lane >> 4;
    int rowA = blockIdx.x * 64 + wave * 16 + m;    // grid exactly 782
    int rA = min(rowA, N - 1);

    bf16x8 afr[4];
    const float* p = A + (size_t)rA * K + quad * 8;
#pragma unroll
    for (int s = 0; s < 4; ++s) {
        float4 lo = *(const float4*)(p + s * 32);
        float4 hi = *(const float4*)(p + s * 32 + 4);
        bf16x8 r;
        r[0] = (short)f2bf(lo.x); r[1] = (short)f2bf(lo.y);
        r[2] = (short)f2bf(lo.z); r[3] = (short)f2bf(lo.w);
        r[4] = (short)f2bf(hi.x); r[5] = (short)f2bf(hi.y);
        r[6] = (short)f2bf(hi.z); r[7] = (short)f2bf(hi.w);
        afr[s] = r;
    }

    f32x4 acc[NT];
#pragma unroll
    for (int t = 0; t < NT; ++t) { acc[t][0] = 0.f; acc[t][1] = 0.f; acc[t][2] = 0.f; acc[t][3] = 0.f; }
#pragma unroll
    for (int t = 0; t < NT; ++t) {
        const unsigned short* wp = Wt + (size_t)(t * 16 + m) * K + quad * 8;
#pragma unroll
        for (int s = 0; s < 4; ++s) {
            bf16x8 bfr = *(const bf16x8*)(wp + s * 32);
            acc[t] = __builtin_amdgcn_mfma_f32_16x16x32_bf16(afr[s], bfr, acc[t], 0, 0, 0);
        }
    }

    int outRowBase = blockIdx.x * 64 + wave * 16 + quad * 4;
    float di[4];
#pragma unroll
    for (int i = 0; i < 4; ++i) di[i] = rsqrtf((float)deg[min(outRowBase + i, N - 1)] + 1.0f);
#pragma unroll
    for (int t = 0; t < NT; ++t)
#pragma unroll
        for (int i = 0; i < 4; ++i) {
            int rr = outRowBase + i;
            if (rr < N) Outb[(size_t)rr * 128 + t * 16 + m] = f2bf(acc[t][i] * di[i]);
        }
}

// ---- FUSED agg+gemm (R15: depth-4 batches + forced 8 waves/EU) ----
// R14 post-mortem: VGPR 68 crossed the 64 boundary -> 4 waves/SIMD (occ 28%),
// net regression. R15: vv[4] only (16 VGPR), __launch_bounds__(256,8) forces
// <=64 VGPR. perm32 colp layout: batch A (4 loads) = logical slots 0..15
// (sufficient when deg<=16, P=.57); batch B = 16..31 behind one wave-uniform
// branch; rare tail >32. Next node's slot-list prefetched during batch A.
template <int M_>
__global__ __launch_bounds__(256, 8) void k_agg_gemm(
        const unsigned short* __restrict__ hs, const int* __restrict__ deg,
        const unsigned short* __restrict__ colp, const float* __restrict__ bias,
        const unsigned short* __restrict__ Wt, unsigned short* __restrict__ Outb) {
    constexpr int K = 128;          // agg feature width and gemm K
    constexpr int NT = M_ / 64;     // col tiles per wave: 128->2, 64->1
    __shared__ __align__(16) unsigned short As[16][136];
    int tid = threadIdx.x;
    int lane = tid & 63, wave = tid >> 6;
    int tileBase = blockIdx.x * 16;
    int g = lane >> 4, c = lane & 15;
    const unsigned short* hc = hs + c * 8;
    int nodeB = tileBase + wave * 4;

    int degv[4], cnt[4];
#pragma unroll
    for (int t = 0; t < 4; ++t) { degv[t] = deg[nodeB + t]; cnt[t] = min(degv[t], SLOTS); }

    u16x8 sl = *(const u16x8*)(colp + (unsigned)nodeB * SLOTS + g * 8);
    unsigned int smk = (g == 0) ? 0xffffffffu : 0u;   // self-term mask

    // ---- agg phase: wave aggregates rows wave*4 .. wave*4+3 ----
#pragma unroll
    for (int t = 0; t < 4; ++t) {
        int r = wave * 4 + t;
        int node = nodeB + t;

        u32x4 sv = *(const u32x4*)(hc + (unsigned)node * K);
        u32x4 vv[4];
#pragma unroll
        for (int k2 = 0; k2 < 4; ++k2)
            vv[k2] = *(const u32x4*)(hc + (unsigned)sl[k2] * K);
        u16x8 sln = sl;
        if (t < 3) sln = *(const u16x8*)(colp + (unsigned)(node + 1) * SLOTS + g * 8);

        float acc[8];
#pragma unroll
        for (int k = 0; k < 4; ++k) {
            unsigned int xv = sv[k] & smk;
            acc[2 * k] = bflo(xv); acc[2 * k + 1] = bfhi(xv);
        }
#pragma unroll
        for (int k2 = 0; k2 < 4; ++k2) {
            unsigned int mk = (4 * k2 + g < cnt[t]) ? 0xffffffffu : 0u;
#pragma unroll
            for (int k = 0; k < 4; ++k) {
                unsigned int xv = vv[k2][k] & mk;
                acc[2 * k] += bflo(xv); acc[2 * k + 1] += bfhi(xv);
            }
        }
        if (cnt[t] > 16) {      // batch B: logical slots 16..31
#pragma unroll
            for (int k2 = 0; k2 < 4; ++k2)
                vv[k2] = *(const u32x4*)(hc + (unsigned)sl[k2 + 4] * K);
#pragma unroll
            for (int k2 = 0; k2 < 4; ++k2) {
                unsigned int mk = (16 + 4 * k2 + g < cnt[t]) ? 0xffffffffu : 0u;
#pragma unroll
                for (int k = 0; k < 4; ++k) {
                    unsigned int xv = vv[k2][k] & mk;
                    acc[2 * k] += bflo(xv); acc[2 * k + 1] += bfhi(xv);
                }
            }
        }
        if (cnt[t] > 32) {      // rare tail (physical >=32 == logical)
            int mi = (lane < cnt[t]) ? (int)colp[(unsigned)node * SLOTS + lane] : 0;
            for (int j = 32; j < cnt[t]; j += 4) {
                int i0 = __shfl(mi, j + g, 64);
                u32x4 v0 = {0, 0, 0, 0};
                if (j + g < cnt[t]) v0 = *(const u32x4*)(hc + (unsigned)i0 * K);
#pragma unroll
                for (int k = 0; k < 4; ++k) {
                    acc[2 * k] += bflo(v0[k]); acc[2 * k + 1] += bfhi(v0[k]);
                }
            }
        }
        sl = sln;

        // cross-group reduce: groups {0,1,2,3} hold partial sums of same dims
#pragma unroll
        for (int k = 0; k < 8; ++k) {
            acc[k] += __shfl_xor(acc[k], 16, 64);
            acc[k] += __shfl_xor(acc[k], 32, 64);
        }
        if (g == 0) {
            float di = rsqrtf((float)degv[t] + 1.0f);
            const float4* bp = (const float4*)(bias + c * 8);
            float4 b0 = bp[0], b1 = bp[1];
            float bb[8] = {b0.x, b0.y, b0.z, b0.w, b1.x, b1.y, b1.z, b1.w};
            u32x4 pv;
#pragma unroll
            for (int k = 0; k < 4; ++k) {
                float o0 = fmaxf(di * acc[2 * k]     + bb[2 * k],     0.f);
                float o1 = fmaxf(di * acc[2 * k + 1] + bb[2 * k + 1], 0.f);
                pv[k] = (unsigned int)f2bf(o0) | ((unsigned int)f2bf(o1) << 16);
            }
            *(u32x4*)&As[r][c * 8] = pv;   // 16B aligned: 136*2*r % 16 == 0
        }
    }
    __syncthreads();

    // ---- gemm phase: 16 rows x M_ cols from LDS A-tile ----
    int m = lane & 15, quad = lane >> 4;
    bf16x8 afr[4];
#pragma unroll
    for (int s = 0; s < 4; ++s)
        afr[s] = *(const bf16x8*)&As[m][s * 32 + quad * 8];

    f32x4 gacc[NT];
#pragma unroll
    for (int t = 0; t < NT; ++t) { gacc[t][0] = 0.f; gacc[t][1] = 0.f; gacc[t][2] = 0.f; gacc[t][3] = 0.f; }
#pragma unroll
    for (int t = 0; t < NT; ++t) {
        int ct = wave * NT + t;     // col tile 0..M_/16-1
        const unsigned short* wp = Wt + (size_t)(ct * 16 + m) * K + quad * 8;
#pragma unroll
        for (int s = 0; s < 4; ++s) {
            bf16x8 bfr = *(const bf16x8*)(wp + s * 32);
            gacc[t] = __builtin_amdgcn_mfma_f32_16x16x32_bf16(afr[s], bfr, gacc[t], 0, 0, 0);
        }
    }

    int rowBase = tileBase + quad * 4;
    float di[4];
#pragma unroll
    for (int i = 0; i < 4; ++i) di[i] = rsqrtf((float)deg[rowBase + i] + 1.0f);
#pragma unroll
    for (int t = 0; t < NT; ++t) {
        int ct = wave * NT + t;
#pragma unroll
        for (int i = 0; i < 4; ++i)
            Outb[(size_t)(rowBase + i) * M_ + ct * 16 + m] = f2bf(gacc[t][i] * di[i]);
    }
}

// ---- final aggregation (F=64, no relu) -> z (bf16) ----
// R15: same 4x16-lane grouping / perm32 layout as k_agg_gemm (8 B per lane,
// u32x2). Batch A covers slots 0..15, batch B 16..31 (cond), tail >32 rare.
__global__ __launch_bounds__(256, 8) void k_agg64(
        const unsigned short* __restrict__ hs, const int* __restrict__ deg,
        const unsigned short* __restrict__ colp, const float* __restrict__ bias,
        unsigned short* __restrict__ out, int n) {
    int tid = threadIdx.x;
    int wave = tid >> 6, lane = tid & 63;
    int node = blockIdx.x * 4 + wave;               // grid exactly 12500
    int g = lane >> 4, c = lane & 15;
    const unsigned short* hc = hs + c * 4;

    int degv = deg[node];
    int cnt = min(degv, SLOTS);
    u16x8 sl = *(const u16x8*)(colp + (unsigned)node * SLOTS + g * 8);

    u32x2 sv = *(const u32x2*)(hc + (unsigned)node * 64);
    u32x2 vv[4];
#pragma unroll
    for (int k2 = 0; k2 < 4; ++k2)
        vv[k2] = *(const u32x2*)(hc + (unsigned)sl[k2] * 64);

    unsigned int smk = (g == 0) ? 0xffffffffu : 0u;
    float acc[4];
#pragma unroll
    for (int k = 0; k < 2; ++k) {
        unsigned int xv = sv[k] & smk;
        acc[2 * k] = bflo(xv); acc[2 * k + 1] = bfhi(xv);
    }
#pragma unroll
    for (int k2 = 0; k2 < 4; ++k2) {
        unsigned int mk = (4 * k2 + g < cnt) ? 0xffffffffu : 0u;
#pragma unroll
        for (int k = 0; k < 2; ++k) {
            unsigned int xv = vv[k2][k] & mk;
            acc[2 * k] += bflo(xv); acc[2 * k + 1] += bfhi(xv);
        }
    }
    if (cnt > 16) {             // batch B: logical slots 16..31
#pragma unroll
        for (int k2 = 0; k2 < 4; ++k2)
            vv[k2] = *(const u32x2*)(hc + (unsigned)sl[k2 + 4] * 64);
#pragma unroll
        for (int k2 = 0; k2 < 4; ++k2) {
            unsigned int mk = (16 + 4 * k2 + g < cnt) ? 0xffffffffu : 0u;
#pragma unroll
            for (int k = 0; k < 2; ++k) {
                unsigned int xv = vv[k2][k] & mk;
                acc[2 * k] += bflo(xv); acc[2 * k + 1] += bfhi(xv);
            }
        }
    }
    if (cnt > 32) {             // rare tail
        int mi = (lane < cnt) ? (int)colp[(unsigned)node * SLOTS + lane] : 0;
        for (int j = 32; j < cnt; j += 4) {
            int i0 = __shfl(mi, j + g, 64);
            u32x2 v0 = {0, 0};
            if (j + g < cnt) v0 = *(const u32x2*)(hc + (unsigned)i0 * 64);
#pragma unroll
            for (int k = 0; k < 2; ++k) {
                acc[2 * k] += bflo(v0[k]); acc[2 * k + 1] += bfhi(v0[k]);
            }
        }
    }
#pragma unroll
    for (int k = 0; k < 4; ++k) {
        acc[k] += __shfl_xor(acc[k], 16, 64);
        acc[k] += __shfl_xor(acc[k], 32, 64);
    }
    if (g == 0) {
        float di = rsqrtf((float)degv + 1.0f);
        float4 bb = *(const float4*)(bias + c * 4);
        u32x2 pv;
        pv[0] = (unsigned int)f2bf(di * acc[0] + bb.x) |
                ((unsigned int)f2bf(di * acc[1] + bb.y) << 16);
        pv[1] = (unsigned int)f2bf(di * acc[2] + bb.z) |
                ((unsigned int)f2bf(di * acc[3] + bb.w) << 16);
        *(u32x2*)(out + (size_t)node * 64 + c * 4) = pv;
    }
}

// ---- decode: out[e] = dot(z[ls[e]], z[ld[e]]) over 64 dims, z bf16 ----
__global__ __launch_bounds__(256) void k_decode(
        const unsigned short* __restrict__ z, const int* __restrict__ ls,
        const int* __restrict__ ld, float* __restrict__ out, int nl) {
    int tid = threadIdx.x;
    int lane = tid & 63, wave = tid >> 6;
    int g = lane >> 3, c = lane & 7;
    int e = (blockIdx.x * 4 + wave) * 4 + (g >> 1);   // grid exactly 6250
    int row = (g & 1) ? ld[e] : ls[e];
    u32x4 v = *(const u32x4*)(z + (size_t)row * 64 + c * 8);
    u32x4 w;
#pragma unroll
    for (int k = 0; k < 4; ++k) w[k] = (unsigned int)__shfl_xor((int)v[k], 8, 64);
    float p = 0.f;
#pragma unroll
    for (int k = 0; k < 4; ++k)
        p += bflo(v[k]) * bflo(w[k]) + bfhi(v[k]) * bfhi(w[k]);
    p += __shfl_xor(p, 1, 64);
    p += __shfl_xor(p, 2, 64);
    p += __shfl_xor(p, 4, 64);
    if ((lane & 15) == 0) out[e] = p;   // lane in {0,16,32,48}: g even, c==0
}

// ================= launcher =================

static inline size_t align256(size_t x) { return (x + 255) & ~(size_t)255; }

extern "C" void kernel_launch(void* const* d_in, const int* in_sizes, int n_in,
                              void* d_out, int out_size, void* d_ws, size_t ws_size,
                              hipStream_t stream) {
    const float* x  = (const float*)d_in[0];
    const int*   ei = (const int*)d_in[1];    // [2][NE]: row0=src, row1=dst
    const int*   li = (const int*)d_in[2];    // [2][NL]
    const float* W1 = (const float*)d_in[3];
    const float* b1 = (const float*)d_in[4];
    const float* W2 = (const float*)d_in[5];
    const float* b2 = (const float*)d_in[6];
    const float* W3 = (const float*)d_in[7];
    const float* b3 = (const float*)d_in[8];
    float* out = (float*)d_out;

    const int* src = ei;
    const int* dst = ei + NE;
    const int* ls = li;
    const int* ld = li + NL;

    // workspace carve-up (~37 MB)
    char* ws = (char*)d_ws;
    size_t off = 0;
    int* deg    = (int*)(ws + off); off += align256(NN * 4);
    int* cursor = (int*)(ws + off); off += align256(NB * 4);
    unsigned int* binbuf = (unsigned int*)(ws + off); off += align256((size_t)NB * BCAP * 4);
    unsigned short* colp = (unsigned short*)(ws + off); off += align256((size_t)NN * SLOTS * 2);
    unsigned short* Wtb  = (unsigned short*)(ws + off); off += align256(40960 * 2);
    unsigned short* bufA = (unsigned short*)(ws + off); off += align256((size_t)NN * 128 * 2);
    unsigned short* bufB = (unsigned short*)(ws + off); off += align256((size_t)NN * 128 * 2);
    unsigned short* bufZ = (unsigned short*)(ws + off); off += align256((size_t)NN * 64 * 2);

    // ---- CSR build + W prep ----
    k_wprep<<<160, 256, 0, stream>>>(W1, W2, W3, Wtb, cursor);
    k_bin<<<391, 256, 0, stream>>>(src, dst, cursor, binbuf);
    k_csr<<<NB, 256, 0, stream>>>(binbuf, cursor, deg, colp);

    // ---- layer 1 GEMM: x -> bufA (h1 = dinv * x@W1, bf16) ----
    k_gemm1<<<782, 256, 0, stream>>>(x, Wtb, deg, bufA, NN);
    // ---- fused agg1(+b1,relu) + gemm2: bufA -> bufB (h2) ----
    k_agg_gemm<128><<<3125, 256, 0, stream>>>(bufA, deg, colp, b1, Wtb + 16384, bufB);
    // ---- fused agg2(+b2,relu) + gemm3: bufB -> bufA (h3, 64-wide) ----
    k_agg_gemm<64><<<3125, 256, 0, stream>>>(bufB, deg, colp, b2, Wtb + 32768, bufA);
    // ---- agg3(+b3, no relu): bufA -> bufZ (z) ----
    k_agg64<<<12500, 256, 0, stream>>>(bufA, deg, colp, b3, bufZ, NN);
    // ---- decode ----
    k_decode<<<6250, 256, 0, stream>>>(bufZ, ls, ld, out, NL);
}

// Round 4
// 231.996 us; speedup vs baseline: 1.0828x; 1.0828x over previous
//
#include <hip/hip_runtime.h>
#include <hip/hip_bf16.h>
#include <stdint.h>

// Problem constants (match reference)
#define NN 50000      // nodes
#define NE 800000     // edges
#define NL 100000     // label edges
#define SLOTS 64      // padded-CSR slots/node (incl. appended self-loop)
#define PADROW 50000  // dedicated all-zero row index in every h-buffer

// Bucketed CSR build (R7: direct scatter was line-bound)
#define NB 196        // dst-range buckets: bucket = dst >> 8 (256 nodes each)
#define BSH 8
#define BCAP 5376     // edges/bucket capacity; mean 4082 -> +20 sigma

typedef __attribute__((ext_vector_type(8))) short bf16x8;   // MFMA A/B frag
typedef __attribute__((ext_vector_type(4))) float f32x4;    // MFMA C/D frag
typedef __attribute__((ext_vector_type(4))) unsigned int u32x4;
typedef __attribute__((ext_vector_type(2))) unsigned int u32x2;
typedef __attribute__((ext_vector_type(8))) unsigned short u16x8;

__device__ __forceinline__ float asf(unsigned int u) {
    union { unsigned int i; float f; } c; c.i = u; return c.f;
}
__device__ __forceinline__ float bflo(unsigned int x) { return asf(x << 16); }
__device__ __forceinline__ float bfhi(unsigned int x) { return asf(x & 0xffff0000u); }
__device__ __forceinline__ unsigned short f2bf(float f) {
    union { float f; unsigned int i; } c; c.f = f;
    unsigned int u = c.i + (0x7fffu + ((c.i >> 16) & 1u));
    return (unsigned short)(u >> 16);
}

// ---- P0: W transpose+convert to bf16 Wt[n][k]; zero cursors + pad rows ----
// R16: also zeroes the PADROW rows of bufA/bufB (row 50000, 128-wide each).
// h3's pad row coincides with bufA's (h3 = bufA upper half), so 2 rows total.
__global__ void k_wprep(const float* __restrict__ W1, const float* __restrict__ W2,
                        const float* __restrict__ W3, unsigned short* __restrict__ Wt,
                        int* __restrict__ cursor, unsigned int* __restrict__ padA,
                        unsigned int* __restrict__ padB) {
    int idx = blockIdx.x * 256 + threadIdx.x;   // grid exactly 160
    if (idx < NB) cursor[idx] = 0;
    if (idx < 64) padA[idx] = 0;
    else if (idx < 128) padB[idx - 64] = 0;
    const float* W; unsigned short* O; int base, Mloc;
    if (idx < 16384)      { W = W1; O = Wt;         base = idx;         Mloc = 128; }
    else if (idx < 32768) { W = W2; O = Wt + 16384; base = idx - 16384; Mloc = 128; }
    else                  { W = W3; O = Wt + 32768; base = idx - 32768; Mloc = 64;  }
    int n = base >> 7, k = base & 127;
    O[base] = f2bf(W[k * Mloc + n]);
}

// ---- P1: bin edges by dst range (LDS histogram -> packed NT writes) ----
__global__ __launch_bounds__(256) void k_bin(
        const int* __restrict__ src, const int* __restrict__ dst,
        int* __restrict__ cursor, unsigned int* __restrict__ binbuf) {
    __shared__ int hcnt[NB];
    __shared__ int hbase[NB];
    __shared__ unsigned int epk[2048];
    int tid = threadIdx.x;
    if (tid < NB) hcnt[tid] = 0;
    __syncthreads();
    int e0 = blockIdx.x * 2048;                 // grid exactly 391
    int e1 = min(e0 + 2048, NE);
    for (int e = e0 + tid; e < e1; e += 256) {
        int d = dst[e], s = src[e];
        atomicAdd(&hcnt[d >> BSH], 1);
        epk[e - e0] = (unsigned int)s | ((unsigned int)d << 16);
    }
    __syncthreads();
    if (tid < NB) { hbase[tid] = atomicAdd(&cursor[tid], hcnt[tid]); hcnt[tid] = 0; }
    __syncthreads();
    for (int e = e0 + tid; e < e1; e += 256) {
        unsigned int pk = epk[e - e0];
        int b = (int)(pk >> 16) >> BSH;
        int p = hbase[b] + atomicAdd(&hcnt[b], 1);
        if (p < BCAP)
            __builtin_nontemporal_store(pk, &binbuf[(size_t)b * BCAP + p]);
    }
}

// ---- P2: per-bucket CSR build in LDS + coalesced flush ----
// R16: (a) pad slots filled with PADROW (gathers read the zero row -> no
// value masks anywhere); (b) node's own id APPENDED at slot p=deg (self-loop
// is algebraically identical to a neighbor since h rows carry dinv).
// Slots < 32 stored PERMUTED: logical slot p at physical 8*(p&3)+(p>>2), so
// lane-group g's contiguous physical [8g,8g+8): element k2 <-> logical 4*k2+g.
__global__ __launch_bounds__(256) void k_csr(
        const unsigned int* __restrict__ binbuf, const int* __restrict__ cursor,
        int* __restrict__ deg, unsigned short* __restrict__ colp) {
    __shared__ unsigned short lcol[256 * SLOTS];   // 32 KB
    __shared__ int ldeg[256];
    int tid = threadIdx.x;
    int blk = blockIdx.x;                          // grid exactly NB
    int base = blk << BSH;
    int nNodes = min(256, NN - base);
    ldeg[tid] = 0;
    const unsigned int fw = 0xC350C350u;           // 2x 50000
    u32x4 fill = {fw, fw, fw, fw};
    u32x4* lz = (u32x4*)lcol;
#pragma unroll
    for (int i = 0; i < 8; ++i) lz[i * 256 + tid] = fill;
    __syncthreads();
    int cnt = min(cursor[blk], BCAP);
    for (int e = tid; e < cnt; e += 256) {
        unsigned int pk = __builtin_nontemporal_load(&binbuf[(size_t)blk * BCAP + e]);
        int d = (int)(pk >> 16) - base;
        int p = atomicAdd(&ldeg[d], 1);
        if (p < SLOTS) {
            int pp = (p < 32) ? ((p & 3) * 8 + (p >> 2)) : p;
            lcol[d * SLOTS + pp] = (unsigned short)(pk & 0xffffu);
        }
    }
    __syncthreads();
    if (tid < nNodes) {
        int dv = ldeg[tid];
        deg[base + tid] = dv;
        if (dv < SLOTS) {                          // append self-loop slot
            int pp = (dv < 32) ? ((dv & 3) * 8 + (dv >> 2)) : dv;
            lcol[tid * SLOTS + pp] = (unsigned short)(base + tid);
        }
    }
    __syncthreads();
    u32x4* gout = (u32x4*)(colp + (size_t)base * SLOTS);
    const u32x4* lin = (const u32x4*)lcol;
    for (int i = tid; i < nNodes * 8; i += 256) gout[i] = lin[i];
}

// ---- layer-1 GEMM: x (fp32) -> bufA (h1). Rows >= NN untouched (pad!) ----
__global__ __launch_bounds__(256) void k_gemm1(
        const float* __restrict__ A, const unsigned short* __restrict__ Wt,
        const int* __restrict__ deg, unsigned short* __restrict__ Outb, int N) {
    constexpr int K = 128;
    constexpr int NT = 8;
    int tid = threadIdx.x;
    int lane = tid & 63, wave = tid >> 6;
    int m = lane & 15, quad = lane >> 4;
    int rowA = blockIdx.x * 64 + wave * 16 + m;    // grid exactly 782
    int rA = min(rowA, N - 1);

    bf16x8 afr[4];
    const float* p = A + (size_t)rA * K + quad * 8;
#pragma unroll
    for (int s = 0; s < 4; ++s) {
        float4 lo = *(const float4*)(p + s * 32);
        float4 hi = *(const float4*)(p + s * 32 + 4);
        bf16x8 r;
        r[0] = (short)f2bf(lo.x); r[1] = (short)f2bf(lo.y);
        r[2] = (short)f2bf(lo.z); r[3] = (short)f2bf(lo.w);
        r[4] = (short)f2bf(hi.x); r[5] = (short)f2bf(hi.y);
        r[6] = (short)f2bf(hi.z); r[7] = (short)f2bf(hi.w);
        afr[s] = r;
    }

    f32x4 acc[NT];
#pragma unroll
    for (int t = 0; t < NT; ++t) { acc[t][0] = 0.f; acc[t][1] = 0.f; acc[t][2] = 0.f; acc[t][3] = 0.f; }
#pragma unroll
    for (int t = 0; t < NT; ++t) {
        const unsigned short* wp = Wt + (size_t)(t * 16 + m) * K + quad * 8;
#pragma unroll
        for (int s = 0; s < 4; ++s) {
            bf16x8 bfr = *(const bf16x8*)(wp + s * 32);
            acc[t] = __builtin_amdgcn_mfma_f32_16x16x32_bf16(afr[s], bfr, acc[t], 0, 0, 0);
        }
    }

    int outRowBase = blockIdx.x * 64 + wave * 16 + quad * 4;
    float di[4];
#pragma unroll
    for (int i = 0; i < 4; ++i) di[i] = rsqrtf((float)deg[min(outRowBase + i, N - 1)] + 1.0f);
#pragma unroll
    for (int t = 0; t < NT; ++t)
#pragma unroll
        for (int i = 0; i < 4; ++i) {
            int rr = outRowBase + i;
            if (rr < N) Outb[(size_t)rr * 128 + t * 16 + m] = f2bf(acc[t][i] * di[i]);
        }
}

// ---- FUSED agg+gemm (R16: mask-free depth-6 gather, no spills) ----
// R15 post-mortem: (256,8) + fat live state -> spills (WRITE_SIZE +17.6MB).
// R16 trims live state: no masks (pad row = zeros), no self special-case
// (self is a CSR slot), depth-6 batch A covers deg<=23 (P=.96) in ONE
// latency exposure; batch B (2 loads, deg<=30), batch C (8 loads, deg<=62),
// all mask-free. Est. ~56 VGPR -> fits 8 waves/SIMD without spilling.
template <int M_>
__global__ __launch_bounds__(256, 8) void k_agg_gemm(
        const unsigned short* __restrict__ hs, const int* __restrict__ deg,
        const unsigned short* __restrict__ colp, const float* __restrict__ bias,
        const unsigned short* __restrict__ Wt, unsigned short* __restrict__ Outb) {
    constexpr int K = 128;          // agg feature width and gemm K
    constexpr int NT = M_ / 64;     // col tiles per wave: 128->2, 64->1
    __shared__ __align__(16) unsigned short As[16][136];
    int tid = threadIdx.x;
    int lane = tid & 63, wave = tid >> 6;
    int tileBase = blockIdx.x * 16;
    int g = lane >> 4, c = lane & 15;
    const unsigned short* hc = hs + c * 8;
    int nodeB = tileBase + wave * 4;

    int4 dg = *(const int4*)(deg + nodeB);         // 16B aligned
    int dgv[4] = {dg.x, dg.y, dg.z, dg.w};

    u16x8 sl = *(const u16x8*)(colp + (unsigned)nodeB * SLOTS + g * 8);

    // ---- agg phase: wave aggregates rows wave*4 .. wave*4+3 ----
#pragma unroll
    for (int t = 0; t < 4; ++t) {
        int node = nodeB + t;
        int su = min(dgv[t] + 1, SLOTS);           // slots incl. self

        u32x4 vv[6];
#pragma unroll
        for (int k2 = 0; k2 < 6; ++k2)
            vv[k2] = *(const u32x4*)(hc + (unsigned)sl[k2] * K);
        u16x8 sln = sl;
        if (t < 3) sln = *(const u16x8*)(colp + (unsigned)(node + 1) * SLOTS + g * 8);

        float acc[8];
#pragma unroll
        for (int k = 0; k < 8; ++k) acc[k] = 0.f;
#pragma unroll
        for (int k2 = 0; k2 < 6; ++k2)
#pragma unroll
            for (int k = 0; k < 4; ++k) {
                acc[2 * k]     += bflo(vv[k2][k]);
                acc[2 * k + 1] += bfhi(vv[k2][k]);
            }
        if (su > 24) {          // batch B: logical slots 24..31
            u32x4 w0 = *(const u32x4*)(hc + (unsigned)sl[6] * K);
            u32x4 w1 = *(const u32x4*)(hc + (unsigned)sl[7] * K);
#pragma unroll
            for (int k = 0; k < 4; ++k) {
                acc[2 * k]     += bflo(w0[k]) + bflo(w1[k]);
                acc[2 * k + 1] += bfhi(w0[k]) + bfhi(w1[k]);
            }
            if (su > 32) {      // batch C: physical slots 32..63 (identity)
                u16x8 s2 = *(const u16x8*)(colp + (unsigned)node * SLOTS + 32 + g * 8);
#pragma unroll
                for (int h = 0; h < 2; ++h) {
                    u32x4 x0 = *(const u32x4*)(hc + (unsigned)s2[4 * h + 0] * K);
                    u32x4 x1 = *(const u32x4*)(hc + (unsigned)s2[4 * h + 1] * K);
                    u32x4 x2 = *(const u32x4*)(hc + (unsigned)s2[4 * h + 2] * K);
                    u32x4 x3 = *(const u32x4*)(hc + (unsigned)s2[4 * h + 3] * K);
#pragma unroll
                    for (int k = 0; k < 4; ++k) {
                        acc[2 * k]     += bflo(x0[k]) + bflo(x1[k]) + bflo(x2[k]) + bflo(x3[k]);
                        acc[2 * k + 1] += bfhi(x0[k]) + bfhi(x1[k]) + bfhi(x2[k]) + bfhi(x3[k]);
                    }
                }
            }
        }
        sl = sln;

        // cross-group reduce: groups {0,1,2,3} hold partial sums of same dims
#pragma unroll
        for (int k = 0; k < 8; ++k) {
            acc[k] += __shfl_xor(acc[k], 16, 64);
            acc[k] += __shfl_xor(acc[k], 32, 64);
        }
        if (g == 0) {
            float di = rsqrtf((float)dgv[t] + 1.0f);
            const float4* bp = (const float4*)(bias + c * 8);
            float4 b0 = bp[0], b1 = bp[1];
            float bb[8] = {b0.x, b0.y, b0.z, b0.w, b1.x, b1.y, b1.z, b1.w};
            u32x4 pv;
#pragma unroll
            for (int k = 0; k < 4; ++k) {
                float o0 = fmaxf(di * acc[2 * k]     + bb[2 * k],     0.f);
                float o1 = fmaxf(di * acc[2 * k + 1] + bb[2 * k + 1], 0.f);
                pv[k] = (unsigned int)f2bf(o0) | ((unsigned int)f2bf(o1) << 16);
            }
            *(u32x4*)&As[wave * 4 + t][c * 8] = pv;   // 16B aligned
        }
    }
    __syncthreads();

    // ---- gemm phase: 16 rows x M_ cols from LDS A-tile ----
    int m = lane & 15, quad = lane >> 4;
    bf16x8 afr[4];
#pragma unroll
    for (int s = 0; s < 4; ++s)
        afr[s] = *(const bf16x8*)&As[m][s * 32 + quad * 8];

    f32x4 gacc[NT];
#pragma unroll
    for (int t = 0; t < NT; ++t) { gacc[t][0] = 0.f; gacc[t][1] = 0.f; gacc[t][2] = 0.f; gacc[t][3] = 0.f; }
#pragma unroll
    for (int t = 0; t < NT; ++t) {
        int ct = wave * NT + t;     // col tile 0..M_/16-1
        const unsigned short* wp = Wt + (size_t)(ct * 16 + m) * K + quad * 8;
#pragma unroll
        for (int s = 0; s < 4; ++s) {
            bf16x8 bfr = *(const bf16x8*)(wp + s * 32);
            gacc[t] = __builtin_amdgcn_mfma_f32_16x16x32_bf16(afr[s], bfr, gacc[t], 0, 0, 0);
        }
    }

    int rowBase = tileBase + quad * 4;
    int4 dg2 = *(const int4*)(deg + rowBase);
    int dgw[4] = {dg2.x, dg2.y, dg2.z, dg2.w};
    float di[4];
#pragma unroll
    for (int i = 0; i < 4; ++i) di[i] = rsqrtf((float)dgw[i] + 1.0f);
#pragma unroll
    for (int t = 0; t < NT; ++t) {
        int ct = wave * NT + t;
#pragma unroll
        for (int i = 0; i < 4; ++i)
            Outb[(size_t)(rowBase + i) * M_ + ct * 16 + m] = f2bf(gacc[t][i] * di[i]);
    }
}

// ---- final aggregation (F=64, no relu) -> z (bf16) ----
// R16: same mask-free depth-6 structure, u32x2 (4 dims/lane, 16 lanes/group).
__global__ __launch_bounds__(256, 8) void k_agg64(
        const unsigned short* __restrict__ hs, const int* __restrict__ deg,
        const unsigned short* __restrict__ colp, const float* __restrict__ bias,
        unsigned short* __restrict__ out, int n) {
    int tid = threadIdx.x;
    int wave = tid >> 6, lane = tid & 63;
    int node = blockIdx.x * 4 + wave;               // grid exactly 12500
    int g = lane >> 4, c = lane & 15;
    const unsigned short* hc = hs + c * 4;

    int degv = deg[node];
    int su = min(degv + 1, SLOTS);
    u16x8 sl = *(const u16x8*)(colp + (unsigned)node * SLOTS + g * 8);

    u32x2 vv[6];
#pragma unroll
    for (int k2 = 0; k2 < 6; ++k2)
        vv[k2] = *(const u32x2*)(hc + (unsigned)sl[k2] * 64);

    float acc[4] = {0.f, 0.f, 0.f, 0.f};
#pragma unroll
    for (int k2 = 0; k2 < 6; ++k2)
#pragma unroll
        for (int k = 0; k < 2; ++k) {
            acc[2 * k]     += bflo(vv[k2][k]);
            acc[2 * k + 1] += bfhi(vv[k2][k]);
        }
    if (su > 24) {              // batch B: logical slots 24..31
        u32x2 w0 = *(const u32x2*)(hc + (unsigned)sl[6] * 64);
        u32x2 w1 = *(const u32x2*)(hc + (unsigned)sl[7] * 64);
#pragma unroll
        for (int k = 0; k < 2; ++k) {
            acc[2 * k]     += bflo(w0[k]) + bflo(w1[k]);
            acc[2 * k + 1] += bfhi(w0[k]) + bfhi(w1[k]);
        }
        if (su > 32) {          // batch C: physical slots 32..63
            u16x8 s2 = *(const u16x8*)(colp + (unsigned)node * SLOTS + 32 + g * 8);
#pragma unroll
            for (int h = 0; h < 2; ++h) {
                u32x2 x0 = *(const u32x2*)(hc + (unsigned)s2[4 * h + 0] * 64);
                u32x2 x1 = *(const u32x2*)(hc + (unsigned)s2[4 * h + 1] * 64);
                u32x2 x2 = *(const u32x2*)(hc + (unsigned)s2[4 * h + 2] * 64);
                u32x2 x3 = *(const u32x2*)(hc + (unsigned)s2[4 * h + 3] * 64);
#pragma unroll
                for (int k = 0; k < 2; ++k) {
                    acc[2 * k]     += bflo(x0[k]) + bflo(x1[k]) + bflo(x2[k]) + bflo(x3[k]);
                    acc[2 * k + 1] += bfhi(x0[k]) + bfhi(x1[k]) + bfhi(x2[k]) + bfhi(x3[k]);
                }
            }
        }
    }
#pragma unroll
    for (int k = 0; k < 4; ++k) {
        acc[k] += __shfl_xor(acc[k], 16, 64);
        acc[k] += __shfl_xor(acc[k], 32, 64);
    }
    if (g == 0) {
        float di = rsqrtf((float)degv + 1.0f);
        float4 bb = *(const float4*)(bias + c * 4);
        u32x2 pv;
        pv[0] = (unsigned int)f2bf(di * acc[0] + bb.x) |
                ((unsigned int)f2bf(di * acc[1] + bb.y) << 16);
        pv[1] = (unsigned int)f2bf(di * acc[2] + bb.z) |
                ((unsigned int)f2bf(di * acc[3] + bb.w) << 16);
        *(u32x2*)(out + (size_t)node * 64 + c * 4) = pv;
    }
}

// ---- decode: out[e] = dot(z[ls[e]], z[ld[e]]) over 64 dims, z bf16 ----
__global__ __launch_bounds__(256) void k_decode(
        const unsigned short* __restrict__ z, const int* __restrict__ ls,
        const int* __restrict__ ld, float* __restrict__ out, int nl) {
    int tid = threadIdx.x;
    int lane = tid & 63, wave = tid >> 6;
    int g = lane >> 3, c = lane & 7;
    int e = (blockIdx.x * 4 + wave) * 4 + (g >> 1);   // grid exactly 6250
    int row = (g & 1) ? ld[e] : ls[e];
    u32x4 v = *(const u32x4*)(z + (size_t)row * 64 + c * 8);
    u32x4 w;
#pragma unroll
    for (int k = 0; k < 4; ++k) w[k] = (unsigned int)__shfl_xor((int)v[k], 8, 64);
    float p = 0.f;
#pragma unroll
    for (int k = 0; k < 4; ++k)
        p += bflo(v[k]) * bflo(w[k]) + bfhi(v[k]) * bfhi(w[k]);
    p += __shfl_xor(p, 1, 64);
    p += __shfl_xor(p, 2, 64);
    p += __shfl_xor(p, 4, 64);
    if ((lane & 15) == 0) out[e] = p;   // lane in {0,16,32,48}: g even, c==0
}

// ================= launcher =================

static inline size_t align256(size_t x) { return (x + 255) & ~(size_t)255; }

extern "C" void kernel_launch(void* const* d_in, const int* in_sizes, int n_in,
                              void* d_out, int out_size, void* d_ws, size_t ws_size,
                              hipStream_t stream) {
    const float* x  = (const float*)d_in[0];
    const int*   ei = (const int*)d_in[1];    // [2][NE]: row0=src, row1=dst
    const int*   li = (const int*)d_in[2];    // [2][NL]
    const float* W1 = (const float*)d_in[3];
    const float* b1 = (const float*)d_in[4];
    const float* W2 = (const float*)d_in[5];
    const float* b2 = (const float*)d_in[6];
    const float* W3 = (const float*)d_in[7];
    const float* b3 = (const float*)d_in[8];
    float* out = (float*)d_out;

    const int* src = ei;
    const int* dst = ei + NE;
    const int* ls = li;
    const int* ld = li + NL;

    // workspace carve-up (~43 MB)
    char* ws = (char*)d_ws;
    size_t off = 0;
    int* deg    = (int*)(ws + off); off += align256(NN * 4);
    int* cursor = (int*)(ws + off); off += align256(NB * 4);
    unsigned int* binbuf = (unsigned int*)(ws + off); off += align256((size_t)NB * BCAP * 4);
    unsigned short* colp = (unsigned short*)(ws + off); off += align256((size_t)NN * SLOTS * 2);
    unsigned short* Wtb  = (unsigned short*)(ws + off); off += align256(40960 * 2);
    // bufA: h1 (128-wide, rows 0..NN-1) + pad row at 50000 (shorts 6.4M..6.4M+128)
    // h3 (64-wide) lives at bufA + 25000*128 shorts; its pad row 50000 is the
    // SAME 128 shorts at 6.4M (zeroed once in k_wprep).
    unsigned short* bufA = (unsigned short*)(ws + off); off += align256(((size_t)NN * 128 + 128) * 2);
    unsigned short* bufB = (unsigned short*)(ws + off); off += align256(((size_t)NN * 128 + 128) * 2);
    unsigned short* bufZ = (unsigned short*)(ws + off); off += align256((size_t)NN * 64 * 2);
    unsigned short* h3 = bufA + (size_t)25000 * 128;

    // ---- CSR build + W prep (+ zero pad rows) ----
    k_wprep<<<160, 256, 0, stream>>>(W1, W2, W3, Wtb, cursor,
                                     (unsigned int*)(bufA + (size_t)PADROW * 128),
                                     (unsigned int*)(bufB + (size_t)PADROW * 128));
    k_bin<<<391, 256, 0, stream>>>(src, dst, cursor, binbuf);
    k_csr<<<NB, 256, 0, stream>>>(binbuf, cursor, deg, colp);

    // ---- layer 1 GEMM: x -> bufA (h1 = dinv * x@W1, bf16) ----
    k_gemm1<<<782, 256, 0, stream>>>(x, Wtb, deg, bufA, NN);
    // ---- fused agg1(+b1,relu) + gemm2: bufA -> bufB (h2) ----
    k_agg_gemm<128><<<3125, 256, 0, stream>>>(bufA, deg, colp, b1, Wtb + 16384, bufB);
    // ---- fused agg2(+b2,relu) + gemm3: bufB -> h3 (64-wide) ----
    k_agg_gemm<64><<<3125, 256, 0, stream>>>(bufB, deg, colp, b2, Wtb + 32768, h3);
    // ---- agg3(+b3, no relu): h3 -> bufZ (z) ----
    k_agg64<<<12500, 256, 0, stream>>>(h3, deg, colp, b3, bufZ, NN);
    // ---- decode ----
    k_decode<<<6250, 256, 0, stream>>>(bufZ, ls, ld, out, NL);
}